// Round 15
// baseline (231.044 us; speedup 1.0000x reference)
//
#include <hip/hip_runtime.h>
#include <math.h>

#define HD 56
#define WD 56
#define CD 64
#define PLANE 3136   // 56*56

typedef _Float16 f16x8 __attribute__((ext_vector_type(8)));
typedef _Float16 f16x4 __attribute__((ext_vector_type(4)));
typedef _Float16 f16x2 __attribute__((ext_vector_type(2)));
typedef float    f32x4 __attribute__((ext_vector_type(4)));

// ---- weight transpose + f16 (6 jobs) ----
__global__ __launch_bounds__(256) void wtrans_k(
    const float* __restrict__ w1, const float* __restrict__ w3, const float* __restrict__ w2,
    const float* __restrict__ ow1, const float* __restrict__ ow3, const float* __restrict__ ow2,
    _Float16* __restrict__ t1, _Float16* __restrict__ t3, _Float16* __restrict__ t2,
    _Float16* __restrict__ owF, _Float16* __restrict__ owT2)
{
    int y = blockIdx.y;
    if (y == 0 || y == 1 || y == 2) {
        const float* src = (y == 0) ? w1 : (y == 1) ? w3 : w2;
        _Float16* dst    = (y == 0) ? t1 : (y == 1) ? t3 : t2;
        int K2 = (y == 1) ? 25 : 9;
        int total = 64 * 64 * K2;
        for (int idx = blockIdx.x * 256 + threadIdx.x; idx < total; idx += gridDim.x * 256) {
            int k = idx >> 12;
            int o = (idx >> 6) & 63;
            int c = idx & 63;
            dst[idx] = (_Float16)src[(o * 64 + c) * K2 + k];
        }
    } else if (y == 3) {
        int total = 9 * 32 * 64;
        for (int idx = blockIdx.x * 256 + threadIdx.x; idx < total; idx += gridDim.x * 256) {
            int k = idx >> 11;
            int o = (idx >> 6) & 31;
            int c = idx & 63;
            owF[k * 6144 + o * 64 + c] = (o < 18) ? (_Float16)ow1[(o * 64 + c) * 9 + k] : (_Float16)0.f;
        }
    } else if (y == 4) {
        int total = 9 * 64 * 64;
        for (int idx = blockIdx.x * 256 + threadIdx.x; idx < total; idx += gridDim.x * 256) {
            int k = idx >> 12;
            int o = (idx >> 6) & 63;
            int c = idx & 63;
            owF[k * 6144 + (32 + o) * 64 + c] = (o < 50) ? (_Float16)ow3[(o * 64 + c) * 9 + k] : (_Float16)0.f;
        }
    } else {
        int total = 9 * 32 * 64;
        for (int idx = blockIdx.x * 256 + threadIdx.x; idx < total; idx += gridDim.x * 256) {
            int k = idx >> 11;
            int o = (idx >> 6) & 31;
            int c = idx & 63;
            owT2[k * 2048 + o * 64 + c] = (o < 18) ? (_Float16)ow2[(o * 64 + c) * 9 + k] : (_Float16)0.f;
        }
    }
}

// ---- channel transpose to f16: dst[b][pix][c] = (f16)src[b][c][pix] ----
__global__ __launch_bounds__(256) void xt_k(const float* __restrict__ src, _Float16* __restrict__ dst)
{
    int b  = blockIdx.y;
    int px = blockIdx.x * 64 + (threadIdx.x & 63);
    int cg = threadIdx.x >> 6;
    const float* s = src + (size_t)b * CD * PLANE + px;
    f16x8 lo, hi;
#pragma unroll
    for (int i = 0; i < 8; ++i) lo[i] = (_Float16)s[(cg * 16 + i) * PLANE];
#pragma unroll
    for (int i = 0; i < 8; ++i) hi[i] = (_Float16)s[(cg * 16 + 8 + i) * PLANE];
    _Float16* d = dst + ((size_t)b * PLANE + px) * 64 + cg * 16;
    *(f16x8*)d = lo;
    *(f16x8*)(d + 8) = hi;
}

// ---------------- offset conv (f16 MFMA) fused with tapprep (r11-proven) ----------------
template<int NTILES, int OP>
__device__ inline void af_load(const _Float16* __restrict__ ow, int k, int off, f16x8* s) {
    const _Float16* wk = ow + k * (OP * 64);
#pragma unroll
    for (int t = 0; t < NTILES; ++t) s[t] = *(const f16x8*)(wk + (t * 16) * 64 + off);
}

template<int FUSED>
__global__ __launch_bounds__(256) void offc_k(
    const _Float16* __restrict__ src,     // [b][pix][64]
    const _Float16* __restrict__ ow,      // [9][OP][64]
    const float* __restrict__ biasA, const float* __restrict__ biasB,
    uint4* __restrict__ tbl)
{
    constexpr int NTILES = FUSED ? 6 : 2;
    constexpr int OP     = FUSED ? 96 : 32;
    constexpr int NTT    = FUSED ? 34 : 9;
    __shared__ float red[4][NTILES * 4 * 64];

    int tid = threadIdx.x;
    int bid = blockIdx.x;
    int b    = bid & 7;
    int tile = bid >> 3;
    int l = tid & 63;
    int n = l & 15;
    int g = l >> 4;
    int w = tid >> 6;
    int tg = w >> 1;
    int pix = tile * 16 + n;
    int ho = pix / WD, wo = pix - ho * WD;
    int ckoff = (w & 1) * 32 + g * 8;
    int afo = n * 64 + ckoff;
    const _Float16* sp = src + ((size_t)b * PLANE + pix) * 64 + ckoff;

    f32x4 acc[NTILES];
#pragma unroll
    for (int t = 0; t < NTILES; ++t) acc[t] = (f32x4){0.f, 0.f, 0.f, 0.f};

#define NB(K, D) { int ky_=(K)/3-1, kx_=(K)%3-1; int yn_=ho+ky_, xn_=wo+kx_;       \
    f16x8 z_ = {(_Float16)0,(_Float16)0,(_Float16)0,(_Float16)0,                   \
                (_Float16)0,(_Float16)0,(_Float16)0,(_Float16)0};                  \
    D = z_;                                                                        \
    if ((unsigned)yn_ < (unsigned)HD && (unsigned)xn_ < (unsigned)WD)              \
        D = *(const f16x8*)(sp + (ky_ * WD + kx_) * 64); }

#define MFMAS(S, NBV) { _Pragma("unroll")                                          \
    for (int t = 0; t < NTILES; ++t)                                               \
        acc[t] = __builtin_amdgcn_mfma_f32_16x16x32_f16((S)[t], NBV, acc[t], 0, 0, 0); }

    f16x8 sA[NTILES], sB[NTILES];
    if (tg == 0) {
        f16x8 nb0, nb1, nb2, nb3, nb4;
        NB(0, nb0) NB(1, nb1) NB(2, nb2) NB(3, nb3) NB(4, nb4)
        af_load<NTILES, OP>(ow, 0, afo, sA);
        af_load<NTILES, OP>(ow, 1, afo, sB); MFMAS(sA, nb0)
        af_load<NTILES, OP>(ow, 2, afo, sA); MFMAS(sB, nb1)
        af_load<NTILES, OP>(ow, 3, afo, sB); MFMAS(sA, nb2)
        af_load<NTILES, OP>(ow, 4, afo, sA); MFMAS(sB, nb3)
        MFMAS(sA, nb4)
    } else {
        f16x8 nb0, nb1, nb2, nb3;
        NB(5, nb0) NB(6, nb1) NB(7, nb2) NB(8, nb3)
        af_load<NTILES, OP>(ow, 5, afo, sA);
        af_load<NTILES, OP>(ow, 6, afo, sB); MFMAS(sA, nb0)
        af_load<NTILES, OP>(ow, 7, afo, sA); MFMAS(sB, nb1)
        af_load<NTILES, OP>(ow, 8, afo, sB); MFMAS(sA, nb2)
        MFMAS(sB, nb3)
    }
#undef NB
#undef MFMAS

#pragma unroll
    for (int t = 0; t < NTILES; ++t)
#pragma unroll
        for (int rr = 0; rr < 4; ++rr)
            red[w][(t * 4 + rr) * 64 + l] = acc[t][rr];
    __syncthreads();

#pragma unroll
    for (int tt = 0; tt < (NTILES + 3) / 4; ++tt) {
        int t = w + tt * 4;
        if (t < NTILES) {
            float v[4];
#pragma unroll
            for (int rr = 0; rr < 4; ++rr) {
                int ia = (t * 4 + rr) * 64 + l;
                v[rr] = red[0][ia] + red[1][ia] + red[2][ia] + red[3][ia];
            }
            int obase = t * 16 + g * 4;
            bool isB = FUSED && (t >= 2);
            int oc0 = isB ? (obase - 32) : obase;
            const float* bp = isB ? biasB : biasA;
#pragma unroll
            for (int pp = 0; pp < 2; ++pp) {
                int oce = oc0 + pp * 2;
                int kl  = oce >> 1;
                int kmax = isB ? 25 : 9;
                if (kl < kmax) {
                    float dy = v[pp * 2]     + bp[oce];
                    float dx = v[pp * 2 + 1] + bp[oce + 1];
                    int by, bx;
                    if (isB) { int q = kl / 5; by = q * 2 - 4; bx = (kl - q * 5) * 2 - 4; }
                    else     { int q = kl / 3; by = q * 2 - 2; bx = (kl - q * 3) * 2 - 2; }
                    float py = dy + (float)(by + ho);
                    float px = dx + (float)(bx + wo);
                    float fy = floorf(py), fx = floorf(px);
                    float wy1 = py - fy, wx1 = px - fx;
                    float wy0 = 1.f - wy1, wx0 = 1.f - wx1;
                    int y0 = (int)fy, x0 = (int)fx;
                    int y1 = y0 + 1, x1 = x0 + 1;
                    float vy0 = (y0 >= 0 && y0 < HD) ? 1.f : 0.f;
                    float vy1 = (y1 >= 0 && y1 < HD) ? 1.f : 0.f;
                    float vx0 = (x0 >= 0 && x0 < WD) ? 1.f : 0.f;
                    float vx1 = (x1 >= 0 && x1 < WD) ? 1.f : 0.f;
                    int cy0 = min(max(y0, 0), HD - 1), cy1 = min(max(y1, 0), HD - 1);
                    int cx0 = min(max(x0, 0), WD - 1), cx1 = min(max(x1, 0), WD - 1);
                    unsigned i00 = (unsigned)(cy0 * WD + cx0), i01 = (unsigned)(cy0 * WD + cx1);
                    unsigned i10 = (unsigned)(cy1 * WD + cx0), i11 = (unsigned)(cy1 * WD + cx1);
                    f16x2 wl = {(_Float16)(wy0 * wx0 * vy0 * vx0), (_Float16)(wy0 * wx1 * vy0 * vx1)};
                    f16x2 wh = {(_Float16)(wy1 * wx0 * vy1 * vx0), (_Float16)(wy1 * wx1 * vy1 * vx1)};
                    uint4 e;
                    e.x = i00 | (i01 << 16);
                    e.y = i10 | (i11 << 16);
                    e.z = __builtin_bit_cast(unsigned int, wl);
                    e.w = __builtin_bit_cast(unsigned int, wh);
                    int gtap = isB ? (9 + kl) : kl;
                    tbl[((size_t)(b * NTT + gtap)) * PLANE + pix] = e;
                }
            }
        }
    }
}

// ---------------- deformable conv + BN: 2 tiles/wave, A/B-aligned tap groups ----------------
// MERGED==1: block 384 = 6 waves {tg: A(9) / B(12) / B(13)} x {kh}; outh f16 [pix][64].
// MERGED==0: block 256 = 4 waves {tg: 5 / 4} x {kh}; out fp32 NCHW = relu(bn+addsrc).
// Wave: 2 pixel-tiles (32 px) x 64 o x its K-half x its tap range; A-frags shared by
// both tiles (af requests halved vs 1-tile waves). Single acc set per wave (A or B).
// Depth-1 rotation pipeline (r11-proven). (NW-1)-way LDS reduce, 1 barrier.
template<int MERGED>
__global__ __launch_bounds__(MERGED ? 384 : 256) void dconv_k(
    const _Float16* __restrict__ xt,      // [b][pix][64] f16
    const uint4* __restrict__ tbl,        // [b][NT][PLANE]
    const _Float16* __restrict__ wTA, const _Float16* __restrict__ wTB, // [k][o][c]
    const float* __restrict__ gA, const float* __restrict__ bA,
    const float* __restrict__ mA, const float* __restrict__ vA,
    const float* __restrict__ gB, const float* __restrict__ bB,
    const float* __restrict__ mB, const float* __restrict__ vB,
    const float* __restrict__ addsrc, float* __restrict__ out,
    _Float16* __restrict__ outh)
{
    constexpr int NT = MERGED ? 34 : 9;
    constexpr int NP = MERGED ? 5 : 3;    // partial-writer count
    __shared__ float red[NP][2][16 * 64];

    int tid = threadIdx.x;
    int bid = blockIdx.x;
    int b    = bid & 7;
    int tp2  = bid >> 3;
    int l = tid & 63, n = l & 15, g = l >> 4;
    int w = tid >> 6;
    int kh = w & 1;
    int tg = w >> 1;
    int pix0 = tp2 * 32 + n;
    int ckoff = kh * 32 + g * 8;

    int base, cnt;
    bool isA;
    if (MERGED) {
        base = (tg == 0) ? 0 : (tg == 1) ? 9 : 21;
        cnt  = (tg == 0) ? 9 : (tg == 1) ? 12 : 13;
        isA  = (tg == 0);
    } else {
        base = tg ? 5 : 0; cnt = tg ? 4 : 5; isA = true;
    }
    const _Float16* wTb = isA ? wTA : wTB;
    int kofs = isA ? 0 : 9;               // weight tap index = tap - kofs

    const _Float16* xp = xt + (size_t)b * PLANE * 64 + ckoff;
    const uint4* tpp = tbl + (size_t)b * NT * PLANE + pix0;   // tile1 entry = +16
    int afoff = n * 64 + ckoff;

    f32x4 acc[2][4];
#pragma unroll
    for (int t = 0; t < 2; ++t)
#pragma unroll
        for (int q = 0; q < 4; ++q) acc[t][q] = (f32x4){0.f, 0.f, 0.f, 0.f};

    f16x8 v[2][4], af4[4];
    uint4 ecur[2];
    unsigned wz[2], ww[2];

    // ---- prologue (tap = base) ----
    {
        uint4 e00 = tpp[base * PLANE];
        uint4 e01 = tpp[base * PLANE + 16];
        int t1 = (cnt > 1) ? base + 1 : base;
        ecur[0] = tpp[t1 * PLANE];
        ecur[1] = tpp[t1 * PLANE + 16];
        uint4 ee[2] = {e00, e01};
#pragma unroll
        for (int t = 0; t < 2; ++t) {
            unsigned i00 = ee[t].x & 0xffffu, i01 = ee[t].x >> 16;
            unsigned i10 = ee[t].y & 0xffffu, i11 = ee[t].y >> 16;
            v[t][0] = *(const f16x8*)(xp + i00 * 64);
            v[t][1] = *(const f16x8*)(xp + i01 * 64);
            v[t][2] = *(const f16x8*)(xp + i10 * 64);
            v[t][3] = *(const f16x8*)(xp + i11 * 64);
            wz[t] = ee[t].z; ww[t] = ee[t].w;
        }
        const _Float16* wk = wTb + (base - kofs) * 4096;
#pragma unroll
        for (int q = 0; q < 4; ++q) af4[q] = *(const f16x8*)(wk + afoff + q * 1024);
    }

#pragma unroll 2
    for (int j = 0; j < cnt; ++j) {
        int tap = base + j;
        bool hn = (j + 1 < cnt);
        f16x8 nv[2][4], naf[4];
        uint4 enxt[2];
        if (hn) {
            int t2 = (j + 2 < cnt) ? (tap + 2) : (base + cnt - 1);
            enxt[0] = tpp[t2 * PLANE];                      // entries(t+2) FIRST
            enxt[1] = tpp[t2 * PLANE + 16];
#pragma unroll
            for (int t = 0; t < 2; ++t) {
                unsigned i00 = ecur[t].x & 0xffffu, i01 = ecur[t].x >> 16;
                unsigned i10 = ecur[t].y & 0xffffu, i11 = ecur[t].y >> 16;
                nv[t][0] = *(const f16x8*)(xp + i00 * 64);  // corners(t+1)
                nv[t][1] = *(const f16x8*)(xp + i01 * 64);
                nv[t][2] = *(const f16x8*)(xp + i10 * 64);
                nv[t][3] = *(const f16x8*)(xp + i11 * 64);
            }
            const _Float16* wk = wTb + (tap + 1 - kofs) * 4096;
#pragma unroll
            for (int q = 0; q < 4; ++q) naf[q] = *(const f16x8*)(wk + afoff + q * 1024);
        }
#pragma unroll
        for (int t = 0; t < 2; ++t) {
            f16x2 wl = __builtin_bit_cast(f16x2, wz[t]);
            f16x2 wh = __builtin_bit_cast(f16x2, ww[t]);
            f16x8 bf = v[t][0] * wl.x + v[t][1] * wl.y + v[t][2] * wh.x + v[t][3] * wh.y;
#pragma unroll
            for (int q = 0; q < 4; ++q)
                acc[t][q] = __builtin_amdgcn_mfma_f32_16x16x32_f16(af4[q], bf, acc[t][q], 0, 0, 0);
        }
        if (hn) {
#pragma unroll
            for (int t = 0; t < 2; ++t) {
#pragma unroll
                for (int c = 0; c < 4; ++c) v[t][c] = nv[t][c];
                wz[t] = ecur[t].z; ww[t] = ecur[t].w;
                ecur[t] = enxt[t];
            }
#pragma unroll
            for (int q = 0; q < 4; ++q) af4[q] = naf[q];
        }
    }

    // reduce: waves w=1..NW-1 write partials; wave 0 (A, kh=0) sums + epilogue
    if (w > 0) {
#pragma unroll
        for (int t = 0; t < 2; ++t)
#pragma unroll
            for (int ot = 0; ot < 4; ++ot)
#pragma unroll
                for (int rr = 0; rr < 4; ++rr)
                    red[w - 1][t][(ot * 4 + rr) * 64 + l] = acc[t][ot][rr];
    }
    __syncthreads();
    if (w == 0) {
#pragma unroll
        for (int t = 0; t < 2; ++t) {
            int pix = pix0 + t * 16;
#pragma unroll
            for (int ot = 0; ot < 4; ++ot) {
                float r[4];
#pragma unroll
                for (int rr = 0; rr < 4; ++rr) {
                    int ia = (ot * 4 + rr) * 64 + l;
                    int o = ot * 16 + g * 4 + rr;
                    if (MERGED) {
                        // A = this wave + red[0] (A,kh1); B = red[1..4]
                        float sumA = acc[t][ot][rr] + red[0][t][ia];
                        float sumB = red[1][t][ia] + red[2][t][ia] + red[3][t][ia] + red[4][t][ia];
                        float ivA = gA[o] * (1.f / sqrtf(vA[o] + 1e-5f));
                        float shA = bA[o] - mA[o] * ivA;
                        float ivB = gB[o] * (1.f / sqrtf(vB[o] + 1e-5f));
                        float shB = bB[o] - mB[o] * ivB;
                        r[rr] = fmaxf(sumA * ivA + shA, 0.f) + fmaxf(sumB * ivB + shB, 0.f);
                    } else {
                        float s = acc[t][ot][rr] + red[0][t][ia] + red[1][t][ia] + red[2][t][ia];
                        float iv = gA[o] * (1.f / sqrtf(vA[o] + 1e-5f));
                        float sh = bA[o] - mA[o] * iv;
                        size_t oidx = (size_t)(b * 64 + o) * PLANE + pix;
                        out[oidx] = fmaxf(s * iv + sh + addsrc[oidx], 0.f);
                    }
                }
                if (MERGED) {
                    f16x4 hv = {(_Float16)r[0], (_Float16)r[1], (_Float16)r[2], (_Float16)r[3]};
                    *(f16x4*)(outh + ((size_t)b * PLANE + pix) * 64 + ot * 16 + g * 4) = hv;
                }
            }
        }
    }
}

extern "C" void kernel_launch(void* const* d_in, const int* in_sizes, int n_in,
                              void* d_out, int out_size, void* d_ws, size_t ws_size,
                              hipStream_t stream) {
    const float* x   = (const float*)d_in[0];
    const float* ow1 = (const float*)d_in[1];
    const float* ob1 = (const float*)d_in[2];
    const float* ow3 = (const float*)d_in[3];
    const float* ob3 = (const float*)d_in[4];
    const float* ow2 = (const float*)d_in[5];
    const float* ob2 = (const float*)d_in[6];
    const float* w1  = (const float*)d_in[7];
    const float* w3  = (const float*)d_in[8];
    const float* w2  = (const float*)d_in[9];
    const float* g1  = (const float*)d_in[10];
    const float* b1  = (const float*)d_in[11];
    const float* m1  = (const float*)d_in[12];
    const float* v1  = (const float*)d_in[13];
    const float* g3  = (const float*)d_in[14];
    const float* b3  = (const float*)d_in[15];
    const float* m3  = (const float*)d_in[16];
    const float* v3  = (const float*)d_in[17];
    const float* g2  = (const float*)d_in[18];
    const float* b2  = (const float*)d_in[19];
    const float* m2  = (const float*)d_in[20];
    const float* v2  = (const float*)d_in[21];

    float* out = (float*)d_out;
    float* ws  = (float*)d_ws;

    // ws layout (float units)
    _Float16* xth  = (_Float16*)ws;                 // 1,605,632 f16 = 802,816 fl
    _Float16* mth  = (_Float16*)(ws + 802816);      // 1,605,632 f16
    uint4*    tbl  = (uint4*)(ws + 1605632);        // 852,992 x 16B (34-tap; 9-tap reuses prefix)
    _Float16* wT1h = (_Float16*)(ws + 5017600);     // 36,864 f16
    _Float16* wT3h = wT1h + 36864;                  // 102,400 f16
    _Float16* wT2h = wT3h + 102400;                 // 36,864 f16
    _Float16* owFh = wT2h + 36864;                  // 9*96*64 = 55,296 f16
    _Float16* owT2h= owFh + 55296;                  // 9*32*64 = 18,432 f16

    wtrans_k<<<dim3(16, 6), dim3(256), 0, stream>>>(
        w1, w3, w2, ow1, ow3, ow2, wT1h, wT3h, wT2h, owFh, owT2h);
    xt_k<<<dim3(49, 8), dim3(256), 0, stream>>>(x, xth);

    offc_k<1><<<dim3(1568), dim3(256), 0, stream>>>(xth, owFh, ob1, ob3, tbl);

    dconv_k<1><<<dim3(784), dim3(384), 0, stream>>>(
        xth, tbl, wT1h, wT3h, g1, b1, m1, v1, g3, b3, m3, v3, nullptr, nullptr, mth);

    offc_k<0><<<dim3(1568), dim3(256), 0, stream>>>(mth, owT2h, ob2, ob2, tbl);

    dconv_k<0><<<dim3(784), dim3(256), 0, stream>>>(
        mth, tbl, wT2h, wT2h, g2, b2, m2, v2, g2, b2, m2, v2, x, out, nullptr);
}

// Round 16
// 200.117 us; speedup vs baseline: 1.1545x; 1.1545x over previous
//
#include <hip/hip_runtime.h>
#include <math.h>

#define HD 56
#define WD 56
#define CD 64
#define PLANE 3136   // 56*56

typedef _Float16 f16x8 __attribute__((ext_vector_type(8)));
typedef _Float16 f16x4 __attribute__((ext_vector_type(4)));
typedef _Float16 f16x2 __attribute__((ext_vector_type(2)));
typedef float    f32x4 __attribute__((ext_vector_type(4)));

// ---- weight transpose + f16 (6 jobs) ----
__global__ __launch_bounds__(256) void wtrans_k(
    const float* __restrict__ w1, const float* __restrict__ w3, const float* __restrict__ w2,
    const float* __restrict__ ow1, const float* __restrict__ ow3, const float* __restrict__ ow2,
    _Float16* __restrict__ t1, _Float16* __restrict__ t3, _Float16* __restrict__ t2,
    _Float16* __restrict__ owF, _Float16* __restrict__ owT2)
{
    int y = blockIdx.y;
    if (y == 0 || y == 1 || y == 2) {
        const float* src = (y == 0) ? w1 : (y == 1) ? w3 : w2;
        _Float16* dst    = (y == 0) ? t1 : (y == 1) ? t3 : t2;
        int K2 = (y == 1) ? 25 : 9;
        int total = 64 * 64 * K2;
        for (int idx = blockIdx.x * 256 + threadIdx.x; idx < total; idx += gridDim.x * 256) {
            int k = idx >> 12;
            int o = (idx >> 6) & 63;
            int c = idx & 63;
            dst[idx] = (_Float16)src[(o * 64 + c) * K2 + k];
        }
    } else if (y == 3) {
        int total = 9 * 32 * 64;
        for (int idx = blockIdx.x * 256 + threadIdx.x; idx < total; idx += gridDim.x * 256) {
            int k = idx >> 11;
            int o = (idx >> 6) & 31;
            int c = idx & 63;
            owF[k * 6144 + o * 64 + c] = (o < 18) ? (_Float16)ow1[(o * 64 + c) * 9 + k] : (_Float16)0.f;
        }
    } else if (y == 4) {
        int total = 9 * 64 * 64;
        for (int idx = blockIdx.x * 256 + threadIdx.x; idx < total; idx += gridDim.x * 256) {
            int k = idx >> 12;
            int o = (idx >> 6) & 63;
            int c = idx & 63;
            owF[k * 6144 + (32 + o) * 64 + c] = (o < 50) ? (_Float16)ow3[(o * 64 + c) * 9 + k] : (_Float16)0.f;
        }
    } else {
        int total = 9 * 32 * 64;
        for (int idx = blockIdx.x * 256 + threadIdx.x; idx < total; idx += gridDim.x * 256) {
            int k = idx >> 11;
            int o = (idx >> 6) & 31;
            int c = idx & 63;
            owT2[k * 2048 + o * 64 + c] = (o < 18) ? (_Float16)ow2[(o * 64 + c) * 9 + k] : (_Float16)0.f;
        }
    }
}

// ---- channel transpose to f16: dst[b][pix][c] = (f16)src[b][c][pix] ----
__global__ __launch_bounds__(256) void xt_k(const float* __restrict__ src, _Float16* __restrict__ dst)
{
    int b  = blockIdx.y;
    int px = blockIdx.x * 64 + (threadIdx.x & 63);
    int cg = threadIdx.x >> 6;
    const float* s = src + (size_t)b * CD * PLANE + px;
    f16x8 lo, hi;
#pragma unroll
    for (int i = 0; i < 8; ++i) lo[i] = (_Float16)s[(cg * 16 + i) * PLANE];
#pragma unroll
    for (int i = 0; i < 8; ++i) hi[i] = (_Float16)s[(cg * 16 + 8 + i) * PLANE];
    _Float16* d = dst + ((size_t)b * PLANE + px) * 64 + cg * 16;
    *(f16x8*)d = lo;
    *(f16x8*)(d + 8) = hi;
}

// ---------------- offset conv (f16 MFMA) fused with tapprep ----------------
template<int FUSED>
__global__ __launch_bounds__(256) void offc_k(
    const _Float16* __restrict__ src,     // [b][pix][64]
    const _Float16* __restrict__ ow,      // [9][OP][64]
    const float* __restrict__ biasA, const float* __restrict__ biasB,
    uint4* __restrict__ tbl)
{
    constexpr int NTILES = FUSED ? 6 : 2;
    constexpr int OP     = FUSED ? 96 : 32;
    constexpr int NTT    = FUSED ? 34 : 9;
    __shared__ float red[4][NTILES * 4 * 64];

    int tid = threadIdx.x;
    int bid = blockIdx.x;
    int b    = bid & 7;
    int tile = bid >> 3;
    int l = tid & 63;
    int n = l & 15;
    int g = l >> 4;
    int w = tid >> 6;
    int tg = w >> 1;
    int pix = tile * 16 + n;
    int ho = pix / WD, wo = pix - ho * WD;
    int ckoff = (w & 1) * 32 + g * 8;
    const _Float16* sp = src + ((size_t)b * PLANE + pix) * 64 + ckoff;

    f32x4 acc[NTILES];
#pragma unroll
    for (int t = 0; t < NTILES; ++t) acc[t] = (f32x4){0.f, 0.f, 0.f, 0.f};

#define OFFC_TAP(K)                                                            \
    {                                                                          \
        int ky = (K) / 3 - 1, kx = (K) % 3 - 1;                                \
        int yn = ho + ky, xn = wo + kx;                                        \
        f16x8 bf = {(_Float16)0, (_Float16)0, (_Float16)0, (_Float16)0,        \
                    (_Float16)0, (_Float16)0, (_Float16)0, (_Float16)0};       \
        if ((unsigned)yn < (unsigned)HD && (unsigned)xn < (unsigned)WD)        \
            bf = *(const f16x8*)(sp + (ky * WD + kx) * 64);                    \
        const _Float16* wk = ow + (K) * (OP * 64);                             \
        _Pragma("unroll")                                                      \
        for (int t = 0; t < NTILES; ++t) {                                     \
            f16x8 af = *(const f16x8*)(wk + (t * 16 + n) * 64 + ckoff);        \
            acc[t] = __builtin_amdgcn_mfma_f32_16x16x32_f16(af, bf, acc[t], 0, 0, 0); \
        }                                                                      \
    }

    if (tg == 0) {
#pragma unroll
        for (int k = 0; k < 5; ++k) OFFC_TAP(k)
    } else {
#pragma unroll
        for (int k = 5; k < 9; ++k) OFFC_TAP(k)
    }
#undef OFFC_TAP

    // all waves write partials, then wave w handles tiles {w, w+4}
#pragma unroll
    for (int t = 0; t < NTILES; ++t)
#pragma unroll
        for (int rr = 0; rr < 4; ++rr)
            red[w][(t * 4 + rr) * 64 + l] = acc[t][rr];
    __syncthreads();

#pragma unroll
    for (int tt = 0; tt < (NTILES + 3) / 4; ++tt) {
        int t = w + tt * 4;
        if (t < NTILES) {
            float v[4];
#pragma unroll
            for (int rr = 0; rr < 4; ++rr) {
                int ia = (t * 4 + rr) * 64 + l;
                v[rr] = red[0][ia] + red[1][ia] + red[2][ia] + red[3][ia];
            }
            int obase = t * 16 + g * 4;
            bool isB = FUSED && (t >= 2);
            int oc0 = isB ? (obase - 32) : obase;
            const float* bp = isB ? biasB : biasA;
#pragma unroll
            for (int pp = 0; pp < 2; ++pp) {
                int oce = oc0 + pp * 2;
                int kl  = oce >> 1;
                int kmax = isB ? 25 : 9;
                if (kl < kmax) {
                    float dy = v[pp * 2]     + bp[oce];
                    float dx = v[pp * 2 + 1] + bp[oce + 1];
                    int by, bx;
                    if (isB) { int q = kl / 5; by = q * 2 - 4; bx = (kl - q * 5) * 2 - 4; }
                    else     { int q = kl / 3; by = q * 2 - 2; bx = (kl - q * 3) * 2 - 2; }
                    float py = dy + (float)(by + ho);
                    float px = dx + (float)(bx + wo);
                    float fy = floorf(py), fx = floorf(px);
                    float wy1 = py - fy, wx1 = px - fx;
                    float wy0 = 1.f - wy1, wx0 = 1.f - wx1;
                    int y0 = (int)fy, x0 = (int)fx;
                    int y1 = y0 + 1, x1 = x0 + 1;
                    float vy0 = (y0 >= 0 && y0 < HD) ? 1.f : 0.f;
                    float vy1 = (y1 >= 0 && y1 < HD) ? 1.f : 0.f;
                    float vx0 = (x0 >= 0 && x0 < WD) ? 1.f : 0.f;
                    float vx1 = (x1 >= 0 && x1 < WD) ? 1.f : 0.f;
                    int cy0 = min(max(y0, 0), HD - 1), cy1 = min(max(y1, 0), HD - 1);
                    int cx0 = min(max(x0, 0), WD - 1), cx1 = min(max(x1, 0), WD - 1);
                    unsigned i00 = (unsigned)(cy0 * WD + cx0), i01 = (unsigned)(cy0 * WD + cx1);
                    unsigned i10 = (unsigned)(cy1 * WD + cx0), i11 = (unsigned)(cy1 * WD + cx1);
                    f16x2 wl = {(_Float16)(wy0 * wx0 * vy0 * vx0), (_Float16)(wy0 * wx1 * vy0 * vx1)};
                    f16x2 wh = {(_Float16)(wy1 * wx0 * vy1 * vx0), (_Float16)(wy1 * wx1 * vy1 * vx1)};
                    uint4 e;
                    e.x = i00 | (i01 << 16);
                    e.y = i10 | (i11 << 16);
                    e.z = __builtin_bit_cast(unsigned int, wl);
                    e.w = __builtin_bit_cast(unsigned int, wh);
                    int gtap = isB ? (9 + kl) : kl;
                    tbl[((size_t)(b * NTT + gtap)) * PLANE + pix] = e;
                }
            }
        }
    }
}

// ---------------- deformable conv + BN: table-driven, K-split AND tap-split ----------------
// MERGED==1: outh = (f16)(relu(bnA(dcA)) + relu(bnB(dcB))), [pix][64] layout (f16 only).
// MERGED==0: out  = relu(bnA(dcA) + addsrc)  (fp32 NCHW)
template<int MERGED>
__global__ __launch_bounds__(256) void dconv_k(
    const _Float16* __restrict__ xt,      // [b][pix][64] f16
    const uint4* __restrict__ tbl,        // [b][NT][PLANE]
    const _Float16* __restrict__ wTA, const _Float16* __restrict__ wTB, // [k][o][c]
    const float* __restrict__ gA, const float* __restrict__ bA,
    const float* __restrict__ mA, const float* __restrict__ vA,
    const float* __restrict__ gB, const float* __restrict__ bB,
    const float* __restrict__ mB, const float* __restrict__ vB,
    const float* __restrict__ addsrc, float* __restrict__ out,
    _Float16* __restrict__ outh)
{
    constexpr int NT   = MERGED ? 34 : 9;
    constexpr int HALF = MERGED ? 17 : 5;
    constexpr int RS   = MERGED ? 32 : 16;
    __shared__ float red[3][RS * 64];

    int tid = threadIdx.x;
    int bid = blockIdx.x;
    int b    = bid & 7;
    int tile = bid >> 3;
    int l   = tid & 63;
    int n   = l & 15;
    int g   = l >> 4;
    int w   = tid >> 6;
    int kh  = w & 1;
    int tg  = w >> 1;
    int pix = tile * 16 + n;
    int ckoff = kh * 32 + g * 8;
    int base = tg ? HALF : 0;
    int cnt  = tg ? (NT - HALF) : HALF;

    const _Float16* xp = xt + (size_t)b * PLANE * 64 + ckoff;
    const uint4*    tp = tbl + (size_t)b * NT * PLANE + pix;
    int afoff = n * 64 + ckoff;

    f32x4 accA[4], accB[4];
#pragma unroll
    for (int ot = 0; ot < 4; ++ot) {
        accA[ot] = (f32x4){0.f, 0.f, 0.f, 0.f};
        accB[ot] = (f32x4){0.f, 0.f, 0.f, 0.f};
    }

    f16x8 v00, v01, v10, v11, af0, af1, af2, af3;
    _Float16 w0, w1, w2, w3;
    uint4 e_cur;

    // ---- prologue (tap = base) ----
    {
        uint4 e0 = tp[base * PLANE];
        int t1 = (cnt > 1) ? base + 1 : base;
        e_cur = tp[t1 * PLANE];
        unsigned i00 = e0.x & 0xffffu, i01 = e0.x >> 16;
        unsigned i10 = e0.y & 0xffffu, i11 = e0.y >> 16;
        v00 = *(const f16x8*)(xp + i00 * 64);
        v01 = *(const f16x8*)(xp + i01 * 64);
        v10 = *(const f16x8*)(xp + i10 * 64);
        v11 = *(const f16x8*)(xp + i11 * 64);
        const _Float16* wk = (!MERGED || base < 9) ? (wTA + base * 4096) : (wTB + (base - 9) * 4096);
        af0 = *(const f16x8*)(wk + afoff);
        af1 = *(const f16x8*)(wk + afoff + 1024);
        af2 = *(const f16x8*)(wk + afoff + 2048);
        af3 = *(const f16x8*)(wk + afoff + 3072);
        f16x2 wl = __builtin_bit_cast(f16x2, e0.z);
        f16x2 wh = __builtin_bit_cast(f16x2, e0.w);
        w0 = wl.x; w1 = wl.y; w2 = wh.x; w3 = wh.y;
    }

#pragma unroll 2
    for (int j = 0; j < cnt; ++j) {
        int tap = base + j;
        bool hn = (j + 1 < cnt);
        f16x8 nv00, nv01, nv10, nv11, naf0, naf1, naf2, naf3;
        uint4 e_nxt;
        if (hn) {
            int t2 = (j + 2 < cnt) ? (tap + 2) : (base + cnt - 1);
            e_nxt = tp[t2 * PLANE];                        // entry(t+2) FIRST
            unsigned i00 = e_cur.x & 0xffffu, i01 = e_cur.x >> 16;
            unsigned i10 = e_cur.y & 0xffffu, i11 = e_cur.y >> 16;
            nv00 = *(const f16x8*)(xp + i00 * 64);         // corners(t+1)
            nv01 = *(const f16x8*)(xp + i01 * 64);
            nv10 = *(const f16x8*)(xp + i10 * 64);
            nv11 = *(const f16x8*)(xp + i11 * 64);
            const _Float16* wk = (!MERGED || tap + 1 < 9) ? (wTA + (tap + 1) * 4096)
                                                          : (wTB + (tap - 8) * 4096);
            naf0 = *(const f16x8*)(wk + afoff);            // A-frags(t+1)
            naf1 = *(const f16x8*)(wk + afoff + 1024);
            naf2 = *(const f16x8*)(wk + afoff + 2048);
            naf3 = *(const f16x8*)(wk + afoff + 3072);
        }
        f16x8 bf = v00 * w0 + v01 * w1 + v10 * w2 + v11 * w3;
        if (!MERGED || tap < 9) {
            accA[0] = __builtin_amdgcn_mfma_f32_16x16x32_f16(af0, bf, accA[0], 0, 0, 0);
            accA[1] = __builtin_amdgcn_mfma_f32_16x16x32_f16(af1, bf, accA[1], 0, 0, 0);
            accA[2] = __builtin_amdgcn_mfma_f32_16x16x32_f16(af2, bf, accA[2], 0, 0, 0);
            accA[3] = __builtin_amdgcn_mfma_f32_16x16x32_f16(af3, bf, accA[3], 0, 0, 0);
        } else {
            accB[0] = __builtin_amdgcn_mfma_f32_16x16x32_f16(af0, bf, accB[0], 0, 0, 0);
            accB[1] = __builtin_amdgcn_mfma_f32_16x16x32_f16(af1, bf, accB[1], 0, 0, 0);
            accB[2] = __builtin_amdgcn_mfma_f32_16x16x32_f16(af2, bf, accB[2], 0, 0, 0);
            accB[3] = __builtin_amdgcn_mfma_f32_16x16x32_f16(af3, bf, accB[3], 0, 0, 0);
        }
        if (hn) {
            v00 = nv00; v01 = nv01; v10 = nv10; v11 = nv11;
            af0 = naf0; af1 = naf1; af2 = naf2; af3 = naf3;
            f16x2 wl = __builtin_bit_cast(f16x2, e_cur.z);
            f16x2 wh = __builtin_bit_cast(f16x2, e_cur.w);
            w0 = wl.x; w1 = wl.y; w2 = wh.x; w3 = wh.y;
            e_cur = e_nxt;
        }
    }

    // 4-way reduce: waves 1..3 write partials, wave 0 sums + epilogue
    if (w > 0) {
#pragma unroll
        for (int ot = 0; ot < 4; ++ot)
#pragma unroll
            for (int rr = 0; rr < 4; ++rr) {
                red[w - 1][(ot * 4 + rr) * 64 + l] = accA[ot][rr];
                if (MERGED) red[w - 1][(16 + ot * 4 + rr) * 64 + l] = accB[ot][rr];
            }
    }
    __syncthreads();
    if (w == 0) {
#pragma unroll
        for (int ot = 0; ot < 4; ++ot) {
            float r[4];
#pragma unroll
            for (int rr = 0; rr < 4; ++rr) {
                int ia = (ot * 4 + rr) * 64 + l;
                float aA = accA[ot][rr] + red[0][ia] + red[1][ia] + red[2][ia];
                int o = ot * 16 + g * 4 + rr;
                float ivA = gA[o] * (1.f / sqrtf(vA[o] + 1e-5f));
                float shA = bA[o] - mA[o] * ivA;
                float vA_ = aA * ivA + shA;
                if (MERGED) {
                    int ib = (16 + ot * 4 + rr) * 64 + l;
                    float aB = accB[ot][rr] + red[0][ib] + red[1][ib] + red[2][ib];
                    float ivB = gB[o] * (1.f / sqrtf(vB[o] + 1e-5f));
                    float shB = bB[o] - mB[o] * ivB;
                    float vB_ = aB * ivB + shB;
                    r[rr] = fmaxf(vA_, 0.f) + fmaxf(vB_, 0.f);
                } else {
                    size_t oidx = (size_t)(b * 64 + o) * PLANE + pix;
                    out[oidx] = fmaxf(vA_ + addsrc[oidx], 0.f);
                }
            }
            if (MERGED) {
                f16x4 hv = {(_Float16)r[0], (_Float16)r[1], (_Float16)r[2], (_Float16)r[3]};
                *(f16x4*)(outh + ((size_t)b * PLANE + pix) * 64 + ot * 16 + g * 4) = hv;
            }
        }
    }
}

extern "C" void kernel_launch(void* const* d_in, const int* in_sizes, int n_in,
                              void* d_out, int out_size, void* d_ws, size_t ws_size,
                              hipStream_t stream) {
    const float* x   = (const float*)d_in[0];
    const float* ow1 = (const float*)d_in[1];
    const float* ob1 = (const float*)d_in[2];
    const float* ow3 = (const float*)d_in[3];
    const float* ob3 = (const float*)d_in[4];
    const float* ow2 = (const float*)d_in[5];
    const float* ob2 = (const float*)d_in[6];
    const float* w1  = (const float*)d_in[7];
    const float* w3  = (const float*)d_in[8];
    const float* w2  = (const float*)d_in[9];
    const float* g1  = (const float*)d_in[10];
    const float* b1  = (const float*)d_in[11];
    const float* m1  = (const float*)d_in[12];
    const float* v1  = (const float*)d_in[13];
    const float* g3  = (const float*)d_in[14];
    const float* b3  = (const float*)d_in[15];
    const float* m3  = (const float*)d_in[16];
    const float* v3  = (const float*)d_in[17];
    const float* g2  = (const float*)d_in[18];
    const float* b2  = (const float*)d_in[19];
    const float* m2  = (const float*)d_in[20];
    const float* v2  = (const float*)d_in[21];

    float* out = (float*)d_out;
    float* ws  = (float*)d_ws;

    // ws layout (float units)
    _Float16* xth  = (_Float16*)ws;                 // 1,605,632 f16 = 802,816 fl
    _Float16* mth  = (_Float16*)(ws + 802816);      // 1,605,632 f16
    uint4*    tbl  = (uint4*)(ws + 1605632);        // 852,992 x 16B (34-tap; 9-tap reuses prefix)
    _Float16* wT1h = (_Float16*)(ws + 5017600);     // 36,864 f16
    _Float16* wT3h = wT1h + 36864;                  // 102,400 f16
    _Float16* wT2h = wT3h + 102400;                 // 36,864 f16
    _Float16* owFh = wT2h + 36864;                  // 9*96*64 = 55,296 f16
    _Float16* owT2h= owFh + 55296;                  // 9*32*64 = 18,432 f16

    wtrans_k<<<dim3(16, 6), dim3(256), 0, stream>>>(
        w1, w3, w2, ow1, ow3, ow2, wT1h, wT3h, wT2h, owFh, owT2h);
    xt_k<<<dim3(49, 8), dim3(256), 0, stream>>>(x, xth);

    offc_k<1><<<dim3(1568), dim3(256), 0, stream>>>(xth, owFh, ob1, ob3, tbl);

    dconv_k<1><<<dim3(1568), dim3(256), 0, stream>>>(
        xth, tbl, wT1h, wT3h, g1, b1, m1, v1, g3, b3, m3, v3, nullptr, nullptr, mth);

    offc_k<0><<<dim3(1568), dim3(256), 0, stream>>>(mth, owT2h, ob2, ob2, tbl);

    dconv_k<0><<<dim3(1568), dim3(256), 0, stream>>>(
        mth, tbl, wT2h, wT2h, g2, b2, m2, v2, g2, b2, m2, v2, x, out, nullptr);
}